// Round 4
// baseline (127942.151 us; speedup 1.0000x reference)
//
#include <hip/hip_runtime.h>
#include <hip/hip_cooperative_groups.h>
#include <cstdint>
#include <cstddef>

namespace cg = cooperative_groups;

// Problem constants
#define BB   64
#define TT   400
#define NN   1024
#define NIN  128
#define NOUT 32
#define DD   3
#define LL   5            // ring length = max(delays)+1, delays = [1,2,4]
#define KT   32           // k-chunks
#define KROWS 96          // rows per k-chunk (32*96 = 3072 = D*N)
#define NTL  8            // n-tiles
#define NCOLS 128         // cols per n-tile

#define ALPHA_MEM     0.95f
#define ALPHA_MEM_OUT 0.95f
#define ALPHA_P       0.99f

// ---------------------------------------------------------------------------
__global__ void build_W(const float* __restrict__ w,
                        const float* __restrict__ w_signs,
                        const float* __restrict__ dmap,
                        float* __restrict__ W) {
    int idx = blockIdx.x * blockDim.x + threadIdx.x;
    if (idx >= DD * NN * NN) return;
    int en = idx % (NN * NN);
    int e  = en / NN;
    W[idx] = dmap[idx] * (w_signs[e] * fabsf(w[en]));
}

__global__ void gemm_in(const float* __restrict__ inputs,
                        const float* __restrict__ w_in,
                        float* __restrict__ inp) {
    int idx = blockIdx.x * blockDim.x + threadIdx.x;   // BB*TT*NN total
    int n  = idx & (NN - 1);
    int bt = idx >> 10;
    const float* row = inputs + (size_t)bt * NIN;
    float acc = 0.0f;
    #pragma unroll 8
    for (int c = 0; c < NIN; ++c)
        acc = fmaf(row[c], w_in[c * NN + n], acc);
    inp[idx] = acc;
}

__global__ void zero_f(float* __restrict__ ptr, int n) {
    int i = blockIdx.x * blockDim.x + threadIdx.x;
    if (i < n) ptr[i] = 0.0f;
}

// ---------------------------------------------------------------------------
// Cooperative per-step GEMM scan. 256 blocks x 1024 threads.
// Phase 1 (all blocks): partial GEMM  part[kt][b][n] over 96 k-rows.
// Phase 2 (blocks 0..63): reduce partials, state update, ring write, hpart.
//          (block 64): readout integration for step t-1.
// ---------------------------------------------------------------------------
__global__ __launch_bounds__(1024, 1) void snn_scan(
    const float* __restrict__ inputs,   // (B,T,NIN)  fallback input proj
    const float* __restrict__ w_in,     // (NIN,N)    fallback input proj
    const float* __restrict__ w_out,    // (N,NOUT)
    const float* __restrict__ p,        // (N)
    const int*   __restrict__ delays,   // (D)
    const float* __restrict__ W,        // (D*N, N) materialized (use_W=1)
    const float* __restrict__ w_raw,    // (N,N)   fallback
    const float* __restrict__ w_signs,  // (N)     fallback
    const float* __restrict__ dmap,     // (D,N,N) fallback
    float*       __restrict__ g_a,      // (LL,N,B) ring of a = out*(1+wp)
    float*       __restrict__ part,     // (KT,B,N) GEMM partials
    float*       __restrict__ hpart,    // (2,64,B,NOUT) readout partials
    const float* __restrict__ inp_pre,  // (B,T,N) or null
    float*       __restrict__ out,      // (B,T,NOUT)
    int use_pre, int use_W)
{
    __shared__ float sA[KROWS * 64];      // 24 KB  a-chunk [96][64b]
    __shared__ float sW[KROWS * NCOLS];   // 48 KB  W-chunk [96][128n]
    __shared__ float sp[16 * 64];         // 4 KB   spike stage [16n][64b]

    cg::grid_group grid = cg::this_grid();

    const int bid = blockIdx.x;
    const int tid = threadIdx.x;

    // GEMM roles
    const int nt = bid >> 5;             // n-tile 0..7
    const int kt = bid & 31;             // k-chunk 0..31
    const int gb = tid >> 4;             // batch 0..63
    const int gg = tid & 15;             // col-group 0..15 (8 cols each)
    const int base_r = kt * KROWS;
    const int ncol0  = nt * NCOLS;

    // state role (blocks 0..63): thread owns one (b, n) state
    const bool is_state = (bid < 64);
    const int  sb = tid >> 4;            // batch
    const int  sn = (bid << 4) | (tid & 15);   // neuron
    float mem = 0.0f, wp = 0.0f, pn = 0.0f, depr = 0.0f;
    if (is_state) { pn = p[sn]; depr = (pn < 0.0f) ? 1.0f : 0.0f; }

    // readout role (block 64): thread owns (b, 2 outs)
    const bool is_ro = (bid == 64);
    const int  rb = tid >> 4;            // batch
    const int  ro = (tid & 15) * 2;      // output pair
    float r0 = 0.0f, r1 = 0.0f;

    const int d0 = delays[0], d1 = delays[1], d2 = delays[2];

    for (int t = 0; t < TT; ++t) {
        const int s0 = (t - d0 + 10) % LL;
        const int s1 = (t - d1 + 10) % LL;
        const int s2 = (t - d2 + 10) % LL;
        const int slot_w = t % LL;

        // ================= phase 1: stage + GEMM =================
        #pragma unroll
        for (int i = 0; i < 6; ++i) {               // A: 96x64 floats
            int flat = i * 1024 + tid;
            int rl = flat >> 6, b = flat & 63;
            int rg = base_r + rl;
            int d  = rg >> 10, e = rg & 1023;
            int slot = (d == 0) ? s0 : ((d == 1) ? s1 : s2);
            sA[rl * 64 + b] = g_a[(size_t)slot * (NN * BB) + e * BB + b];
        }
        if (use_W) {
            #pragma unroll
            for (int i = 0; i < 3; ++i) {           // W: 96x128 floats (3072 f4)
                int flat = i * 1024 + tid;          // float4 index
                int rl = flat >> 5;
                int c  = (flat & 31) << 2;
                const float4 v = *(const float4*)&W[(size_t)(base_r + rl) * NN + ncol0 + c];
                *(float4*)&sW[rl * NCOLS + c] = v;
            }
        } else {
            #pragma unroll
            for (int i = 0; i < 3; ++i) {
                int flat = i * 1024 + tid;
                int rl = flat >> 5;
                int c  = (flat & 31) << 2;
                int rg = base_r + rl;
                int e  = rg & 1023;
                float sgn = w_signs[e];
                float4 dm = *(const float4*)&dmap[(size_t)rg * NN + ncol0 + c];
                float4 wv = *(const float4*)&w_raw[(size_t)e * NN + ncol0 + c];
                float4 o;
                o.x = dm.x * (sgn * fabsf(wv.x));
                o.y = dm.y * (sgn * fabsf(wv.y));
                o.z = dm.z * (sgn * fabsf(wv.z));
                o.w = dm.w * (sgn * fabsf(wv.w));
                *(float4*)&sW[rl * NCOLS + c] = o;
            }
        }
        __syncthreads();

        // prefetch input current for phase 2 (hides HBM latency behind GEMM)
        float ia = 0.0f;
        if (is_state && use_pre)
            ia = inp_pre[((size_t)sb * TT + t) * NN + sn];

        float acc0 = 0.f, acc1 = 0.f, acc2 = 0.f, acc3 = 0.f,
              acc4 = 0.f, acc5 = 0.f, acc6 = 0.f, acc7 = 0.f;
        {
            const float* Ab = sA + gb;
            const float* Wg = sW + gg * 8;
            #pragma unroll 8
            for (int rr = 0; rr < KROWS; rr += 2) {
                const float a0 = Ab[rr * 64];
                const float a1 = Ab[rr * 64 + 64];
                const float4 x0 = *(const float4*)(Wg + rr * NCOLS);
                const float4 x1 = *(const float4*)(Wg + rr * NCOLS + 4);
                const float4 y0 = *(const float4*)(Wg + rr * NCOLS + NCOLS);
                const float4 y1 = *(const float4*)(Wg + rr * NCOLS + NCOLS + 4);
                acc0 = fmaf(a0, x0.x, acc0); acc1 = fmaf(a0, x0.y, acc1);
                acc2 = fmaf(a0, x0.z, acc2); acc3 = fmaf(a0, x0.w, acc3);
                acc4 = fmaf(a0, x1.x, acc4); acc5 = fmaf(a0, x1.y, acc5);
                acc6 = fmaf(a0, x1.z, acc6); acc7 = fmaf(a0, x1.w, acc7);
                acc0 = fmaf(a1, y0.x, acc0); acc1 = fmaf(a1, y0.y, acc1);
                acc2 = fmaf(a1, y0.z, acc2); acc3 = fmaf(a1, y0.w, acc3);
                acc4 = fmaf(a1, y1.x, acc4); acc5 = fmaf(a1, y1.y, acc5);
                acc6 = fmaf(a1, y1.z, acc6); acc7 = fmaf(a1, y1.w, acc7);
            }
        }
        {
            float4 o0 = { acc0, acc1, acc2, acc3 };
            float4 o1 = { acc4, acc5, acc6, acc7 };
            size_t pofs = ((size_t)kt * BB + gb) * NN + ncol0 + gg * 8;
            *(float4*)&part[pofs]     = o0;
            *(float4*)&part[pofs + 4] = o1;
        }
        __threadfence();
        grid.sync();

        // ================= phase 2 =================
        if (is_state) {
            float syn = 0.0f;
            #pragma unroll
            for (int k2 = 0; k2 < KT; ++k2)
                syn += part[((size_t)k2 * BB + sb) * NN + sn];

            if (!use_pre) {
                const float* irow = inputs + ((size_t)sb * TT + t) * NIN;
                #pragma unroll 8
                for (int c = 0; c < NIN; ++c)
                    ia = fmaf(irow[c], w_in[c * NN + sn], ia);
            }

            const bool  spk = (mem - 1.0f) > 0.0f;
            const float a   = spk ? (1.0f + wp) : 0.0f;
            g_a[(size_t)slot_w * (NN * BB) + sn * BB + sb] = a;
            wp  = ALPHA_P * wp + (spk ? pn * (1.0f + depr * wp) : 0.0f);
            mem = ALPHA_MEM * mem + ia + syn - (spk ? 1.0f : 0.0f);

            // readout partial: hpart[t&1][bid][b][o] = sum_{n in tile} spk*w_out
            sp[(tid & 15) * 64 + sb] = spk ? 1.0f : 0.0f;
            __syncthreads();
            const int hb = tid >> 4, og = (tid & 15) * 2;
            float h0 = 0.f, h1 = 0.f;
            #pragma unroll
            for (int nl = 0; nl < 16; ++nl) {
                const float sv = sp[nl * 64 + hb];
                const int   ng = (bid << 4) | nl;
                if (sv > 0.0f) {
                    h0 += w_out[ng * NOUT + og];
                    h1 += w_out[ng * NOUT + og + 1];
                }
            }
            float2 hv = { h0, h1 };
            *(float2*)&hpart[(((size_t)(t & 1) * 64 + bid) * BB + hb) * NOUT + og] = hv;
        }
        if (is_ro && t > 0) {
            const int par = (t - 1) & 1;
            float h0 = 0.f, h1 = 0.f;
            #pragma unroll 8
            for (int s = 0; s < 64; ++s) {
                float2 v = *(const float2*)&hpart[(((size_t)par * 64 + s) * BB + rb) * NOUT + ro];
                h0 += v.x; h1 += v.y;
            }
            r0 = ALPHA_MEM_OUT * r0 + h0;
            r1 = ALPHA_MEM_OUT * r1 + h1;
            float2 rv = { r0, r1 };
            *(float2*)&out[((size_t)rb * TT + (t - 1)) * NOUT + ro] = rv;
        }
        __threadfence();
        grid.sync();
    }

    // final readout step t = TT-1
    if (is_ro) {
        const int par = (TT - 1) & 1;
        float h0 = 0.f, h1 = 0.f;
        #pragma unroll 8
        for (int s = 0; s < 64; ++s) {
            float2 v = *(const float2*)&hpart[(((size_t)par * 64 + s) * BB + rb) * NOUT + ro];
            h0 += v.x; h1 += v.y;
        }
        r0 = ALPHA_MEM_OUT * r0 + h0;
        r1 = ALPHA_MEM_OUT * r1 + h1;
        float2 rv = { r0, r1 };
        *(float2*)&out[((size_t)rb * TT + (TT - 1)) * NOUT + ro] = rv;
    }
}

// ---------------------------------------------------------------------------
extern "C" void kernel_launch(void* const* d_in, const int* in_sizes, int n_in,
                              void* d_out, int out_size, void* d_ws, size_t ws_size,
                              hipStream_t stream) {
    const float* inputs  = (const float*)d_in[0];
    const float* w       = (const float*)d_in[1];
    const float* w_in    = (const float*)d_in[2];
    const float* w_out   = (const float*)d_in[3];
    const float* w_signs = (const float*)d_in[4];
    const float* dmap    = (const float*)d_in[5];
    const float* p       = (const float*)d_in[6];
    const int*   delays  = (const int*)d_in[7];
    float*       outp    = (float*)d_out;

    const size_t ga_b   = (size_t)LL * NN * BB * 4;        // 1.31 MB
    const size_t part_b = (size_t)KT * BB * NN * 4;        // 8.39 MB
    const size_t hp_b   = (size_t)2 * 64 * BB * NOUT * 4;  // 1.05 MB
    const size_t W_b    = (size_t)DD * NN * NN * 4;        // 12.58 MB
    const size_t pre_b  = (size_t)BB * TT * NN * 4;        // 104.86 MB

    char* ws = (char*)d_ws;
    float* g_a   = (float*)ws;                 ws += ga_b;
    float* partp = (float*)ws;                 ws += part_b;
    float* hpart = (float*)ws;                 ws += hp_b;
    size_t used = ga_b + part_b + hp_b;

    int use_W = 0, use_pre = 0;
    float *W = nullptr, *inp_pre = nullptr;
    if (ws_size >= used + W_b) { use_W = 1; W = (float*)ws; ws += W_b; used += W_b; }
    if (ws_size >= used + pre_b) { use_pre = 1; inp_pre = (float*)ws; used += pre_b; }

    if (use_W) {
        const int total = DD * NN * NN;
        build_W<<<(total + 255) / 256, 256, 0, stream>>>(w, w_signs, dmap, W);
    }
    if (use_pre) {
        const int total = BB * TT * NN;
        gemm_in<<<(total + 255) / 256, 256, 0, stream>>>(inputs, w_in, inp_pre);
    }
    {
        const int total = LL * NN * BB;
        zero_f<<<(total + 255) / 256, 256, 0, stream>>>(g_a, total);
    }

    void* args[] = {
        (void*)&inputs, (void*)&w_in, (void*)&w_out, (void*)&p, (void*)&delays,
        (void*)&W, (void*)&w, (void*)&w_signs, (void*)&dmap,
        (void*)&g_a, (void*)&partp, (void*)&hpart, (void*)&inp_pre, (void*)&outp,
        (void*)&use_pre, (void*)&use_W
    };
    hipLaunchCooperativeKernel((const void*)snn_scan,
                               dim3(NTL * KT), dim3(1024), args, 0, stream);
}

// Round 5
// 13411.818 us; speedup vs baseline: 9.5395x; 9.5395x over previous
//
#include <hip/hip_runtime.h>
#include <cstdint>
#include <cstddef>

// Problem constants
#define BB    64
#define TT    400
#define NN    1024
#define NIN   128
#define NOUT  32
#define DD    3
#define LL6   6        // ring length (delays 1,2,4; 6 allows one barrier/step)

#define ALPHA_MEM     0.95f
#define ALPHA_MEM_OUT 0.95f
#define ALPHA_P       0.99f

// ---------------------------------------------------------------------------
__global__ void build_W(const float* __restrict__ w,
                        const float* __restrict__ w_signs,
                        const float* __restrict__ dmap,
                        float* __restrict__ W) {
    int idx = blockIdx.x * blockDim.x + threadIdx.x;
    if (idx >= DD * NN * NN) return;
    int en = idx % (NN * NN);
    int e  = en / NN;
    W[idx] = dmap[idx] * (w_signs[e] * fabsf(w[en]));
}

// inp_pre laid out [t][b][n] for coalesced per-step reads
__global__ void gemm_in(const float* __restrict__ inputs,
                        const float* __restrict__ w_in,
                        float* __restrict__ inp) {
    int idx = blockIdx.x * blockDim.x + threadIdx.x;   // T*B*N total
    if (idx >= TT * BB * NN) return;
    int n  = idx & (NN - 1);
    int tb = idx >> 10;
    int b  = tb & 63;
    int t  = tb >> 6;
    const float* row = inputs + ((size_t)b * TT + t) * NIN;
    float acc = 0.0f;
    #pragma unroll 8
    for (int c = 0; c < NIN; ++c)
        acc = fmaf(row[c], w_in[c * NN + n], acc);
    inp[idx] = acc;
}

// zero ring+counters THROUGH the coherent point (IF), so sc1 readers see it
__global__ void zero_sc1(float* __restrict__ p, int n) {
    int i = blockIdx.x * blockDim.x + threadIdx.x;
    if (i < n)
        __hip_atomic_store(p + i, 0.0f, __ATOMIC_RELAXED, __HIP_MEMORY_SCOPE_AGENT);
}

// ---------------------------------------------------------------------------
// 256 blocks x 256 threads. Block (g = bid>>5, tile = bid&31) owns states for
// batches 8g..8g+7, columns tile*32..+31. Per step:
//   spike + ring publish (sc1) -> group barrier (32 blocks, one atomic) ->
//   stage A (3 slots x 8b x 1024e) from ring (sc1) into LDS ->
//   register-tiled GEMM (8b x 4n per thread, k-split 32) vs L2-resident
//   W tile -> k-reduce in LDS -> state update. Readout folded into tile-0
//   blocks via per-tile hpart partials (sc1).
// ---------------------------------------------------------------------------
__global__ __launch_bounds__(256, 1) void snn_scan(
    const float* __restrict__ inputs,   // (B,T,NIN)   fallback ia
    const float* __restrict__ w_in,     // (NIN,N)     fallback ia
    const float* __restrict__ w_out,    // (N,NOUT)
    const float* __restrict__ p,        // (N)
    const int*   __restrict__ delays,   // (D)
    const float* __restrict__ W,        // (D*N,N) materialized (use_W)
    const float* __restrict__ w_raw,    // (N,N)   fallback
    const float* __restrict__ w_signs,  // (N)     fallback
    const float* __restrict__ dmap,     // (D,N,N) fallback
    float*       __restrict__ ring,     // (LL6,B,N) spike-value ring (IF-coherent)
    int*         __restrict__ cnt,      // (8) group barrier counters
    float*       __restrict__ hpart,    // (2,32,B,NOUT) readout partials
    const float* __restrict__ inp_pre,  // (T,B,N) or null
    float*       __restrict__ out,      // (B,T,NOUT)
    int use_pre, int use_W)
{
    __shared__ float sa[8 * 3072];      // 96 KB; aliased as red[256*33] post-GEMM
    __shared__ float w_out_s[32 * 32];  // 4 KB   w_out rows of this tile
    __shared__ float spk_s[256];        // 1 KB
    __shared__ float s_sign[NN];        // 4 KB   (fallback only)
    __shared__ float s_in[8 * NIN];     // 4 KB   (fallback only)

    const int bid  = blockIdx.x;
    const int g    = bid >> 5;          // batch group 0..7
    const int tile = bid & 31;          // column tile 0..31 (-> XCD tile%8)
    const int tid  = threadIdx.x;

    // state role: (sb, nl)
    const int sb = tid >> 5;            // batch in group 0..7
    const int nl = tid & 31;            // col in tile 0..31
    // GEMM role: (gks, gcg)
    const int gks = tid >> 3;           // k-split 0..31
    const int gcg = tid & 7;            // col group 0..7 (4 cols)

    const bool is_ro = (tile == 0);     // readout role (one block per group)

    const float pn   = p[tile * 32 + nl];
    const float depr = (pn < 0.0f) ? 1.0f : 0.0f;
    const int d0 = delays[0], d1 = delays[1], d2 = delays[2];

    for (int k = tid; k < 1024; k += 256)
        w_out_s[k] = w_out[(tile * 32 + (k >> 5)) * NOUT + (k & 31)];
    if (!use_W)
        for (int k = tid; k < 1024; k += 256) s_sign[k] = w_signs[k];

    float mem = 0.0f, wp = 0.0f, r = 0.0f;
    const float* Wt  = W     + tile * 32 + gcg * 4;
    const float* Dt  = dmap  + tile * 32 + gcg * 4;
    const float* Rt  = w_raw + tile * 32 + gcg * 4;
    __syncthreads();

    for (int t = 0; t < TT; ++t) {
        const int slot_w = t % LL6;
        const int s0 = (t - d0 + 2 * LL6) % LL6;
        const int s1 = (t - d1 + 2 * LL6) % LL6;
        const int s2 = (t - d2 + 2 * LL6) % LL6;

        // ---- phase 1: spike, publish to ring (IF-coherent), wp update
        const bool  spk = (mem - 1.0f) > 0.0f;
        const float a   = spk ? (1.0f + wp) : 0.0f;
        __hip_atomic_store(ring + ((size_t)(slot_w * BB + 8 * g + sb) << 10)
                                + tile * 32 + nl,
                           a, __ATOMIC_RELAXED, __HIP_MEMORY_SCOPE_AGENT);
        wp = ALPHA_P * wp + (spk ? pn * (1.0f + depr * wp) : 0.0f);
        spk_s[tid] = spk ? 1.0f : 0.0f;
        float ia = 0.0f;
        if (use_pre) {
            ia = inp_pre[((size_t)t * BB + 8 * g + sb) * NN + tile * 32 + nl];
        } else {
            for (int k = tid; k < 8 * NIN; k += 256) {
                int b2 = k >> 7, c = k & 127;
                s_in[k] = inputs[((size_t)(8 * g + b2) * TT + t) * NIN + c];
            }
        }
        __syncthreads();

        // ---- phase 2: readout partial for this tile (h = sum_n spk*w_out)
        {
            float h = 0.0f;
            #pragma unroll
            for (int n2 = 0; n2 < 32; ++n2)
                h = fmaf(spk_s[sb * 32 + n2], w_out_s[n2 * 32 + nl], h);
            __hip_atomic_store(hpart + ((((size_t)(t & 1) * 32 + tile) * BB)
                                        + 8 * g + sb) * NOUT + nl,
                               h, __ATOMIC_RELAXED, __HIP_MEMORY_SCOPE_AGENT);
        }
        if (!use_pre) {
            #pragma unroll 8
            for (int c = 0; c < NIN; ++c)
                ia = fmaf(s_in[sb * 128 + c], w_in[c * NN + tile * 32 + nl], ia);
        }
        __syncthreads();   // drains all threads' sc1 stores (vmcnt 0 at barrier)

        // ---- group barrier: 32 blocks, one RMW each, relaxed spin
        if (tid == 0) {
            __hip_atomic_fetch_add(&cnt[g], 1, __ATOMIC_RELEASE,
                                   __HIP_MEMORY_SCOPE_AGENT);
            const int target = 32 * (t + 1);
            while (__hip_atomic_load(&cnt[g], __ATOMIC_RELAXED,
                                     __HIP_MEMORY_SCOPE_AGENT) < target)
                __builtin_amdgcn_s_sleep(2);
        }
        __syncthreads();

        // ---- readout (tile-0 blocks): integrate step t
        if (is_ro) {
            float h = 0.0f;
            for (int k3 = 0; k3 < 32; ++k3)
                h += __hip_atomic_load(hpart + ((((size_t)(t & 1) * 32 + k3) * BB)
                                                + 8 * g + sb) * NOUT + nl,
                                       __ATOMIC_RELAXED, __HIP_MEMORY_SCOPE_AGENT);
            r = ALPHA_MEM_OUT * r + h;
            out[((size_t)(8 * g + sb) * TT + t) * NOUT + nl] = r;
        }

        // ---- stage A: ring slots (d0,d1,d2) x 8 batches x 1024 e -> LDS
        for (int i = 0; i < 96; ++i) {
            const int flat = i * 256 + tid;
            const int sIdx = flat >> 13;
            const int b2   = (flat >> 10) & 7;
            const int e    = flat & 1023;
            const int sl   = (sIdx == 0) ? s0 : ((sIdx == 1) ? s1 : s2);
            const float v  = __hip_atomic_load(
                ring + ((size_t)(sl * BB + 8 * g + b2) << 10) + e,
                __ATOMIC_RELAXED, __HIP_MEMORY_SCOPE_AGENT);
            sa[b2 * 3072 + (sIdx << 10) + e] = v;
        }
        __syncthreads();

        // ---- GEMM: 8b x 4n register tile, k interleaved (kappa = gks + 32 i)
        float4 acc[8];
        #pragma unroll
        for (int b2 = 0; b2 < 8; ++b2) acc[b2] = make_float4(0.f, 0.f, 0.f, 0.f);

        if (use_W) {
            #pragma unroll 4
            for (int i = 0; i < 96; ++i) {
                const int k = gks + (i << 5);
                const float4 wv = *(const float4*)(Wt + ((size_t)k << 10));
                #pragma unroll
                for (int b2 = 0; b2 < 8; ++b2) {
                    const float ab = sa[b2 * 3072 + k];
                    acc[b2].x = fmaf(ab, wv.x, acc[b2].x);
                    acc[b2].y = fmaf(ab, wv.y, acc[b2].y);
                    acc[b2].z = fmaf(ab, wv.z, acc[b2].z);
                    acc[b2].w = fmaf(ab, wv.w, acc[b2].w);
                }
            }
        } else {
            #pragma unroll 2
            for (int i = 0; i < 96; ++i) {
                const int k = gks + (i << 5);
                const int e = k & 1023;
                const float4 dm = *(const float4*)(Dt + ((size_t)k << 10));
                const float4 wr = *(const float4*)(Rt + ((size_t)e << 10));
                const float sg = s_sign[e];
                float4 wv;
                wv.x = dm.x * (sg * fabsf(wr.x));
                wv.y = dm.y * (sg * fabsf(wr.y));
                wv.z = dm.z * (sg * fabsf(wr.z));
                wv.w = dm.w * (sg * fabsf(wr.w));
                #pragma unroll
                for (int b2 = 0; b2 < 8; ++b2) {
                    const float ab = sa[b2 * 3072 + k];
                    acc[b2].x = fmaf(ab, wv.x, acc[b2].x);
                    acc[b2].y = fmaf(ab, wv.y, acc[b2].y);
                    acc[b2].z = fmaf(ab, wv.z, acc[b2].z);
                    acc[b2].w = fmaf(ab, wv.w, acc[b2].w);
                }
            }
        }
        __syncthreads();             // all sa reads done; alias as red

        float* red = sa;             // red[out][33], out = b*32 + cg*4 + j
        #pragma unroll
        for (int b2 = 0; b2 < 8; ++b2) {
            const int o0 = b2 * 32 + gcg * 4;
            red[(o0 + 0) * 33 + gks] = acc[b2].x;
            red[(o0 + 1) * 33 + gks] = acc[b2].y;
            red[(o0 + 2) * 33 + gks] = acc[b2].z;
            red[(o0 + 3) * 33 + gks] = acc[b2].w;
        }
        __syncthreads();

        float syn = 0.0f;
        #pragma unroll
        for (int k2 = 0; k2 < 32; ++k2)
            syn += red[tid * 33 + k2];

        mem = ALPHA_MEM * mem + ia + syn - (spk ? 1.0f : 0.0f);
        __syncthreads();             // red reads done before next-step staging
    }
}

// ---------------------------------------------------------------------------
extern "C" void kernel_launch(void* const* d_in, const int* in_sizes, int n_in,
                              void* d_out, int out_size, void* d_ws, size_t ws_size,
                              hipStream_t stream) {
    const float* inputs  = (const float*)d_in[0];
    const float* w       = (const float*)d_in[1];
    const float* w_in    = (const float*)d_in[2];
    const float* w_out   = (const float*)d_in[3];
    const float* w_signs = (const float*)d_in[4];
    const float* dmap    = (const float*)d_in[5];
    const float* p       = (const float*)d_in[6];
    const int*   delays  = (const int*)d_in[7];
    float*       outp    = (float*)d_out;

    // ws layout (floats): ring | cnt(+pad) | hpart | W | inp_pre
    const size_t ring_f = (size_t)LL6 * BB * NN;          // 393216
    const size_t cnt_f  = 256;
    const size_t hp_f   = (size_t)2 * 32 * BB * NOUT;     // 131072
    const size_t W_f    = (size_t)DD * NN * NN;           // 3145728
    const size_t pre_f  = (size_t)TT * BB * NN;           // 26214400

    float* ws = (float*)d_ws;
    float* ring  = ws;
    int*   cntp  = (int*)(ws + ring_f);
    float* hpart = ws + ring_f + cnt_f;
    size_t used  = ring_f + cnt_f + hp_f;

    int use_W = 0, use_pre = 0;
    float *W = nullptr, *inp_pre = nullptr;
    if (ws_size >= (used + W_f) * 4) { use_W = 1; W = ws + used; used += W_f; }
    if (ws_size >= (used + pre_f) * 4) { use_pre = 1; inp_pre = ws + used; used += pre_f; }

    if (use_W) {
        const int total = DD * NN * NN;
        build_W<<<(total + 255) / 256, 256, 0, stream>>>(w, w_signs, dmap, W);
    }
    if (use_pre) {
        const int total = TT * BB * NN;
        gemm_in<<<(total + 255) / 256, 256, 0, stream>>>(inputs, w_in, inp_pre);
    }
    {
        const int total = (int)(ring_f + cnt_f);   // ring + counters
        zero_sc1<<<(total + 255) / 256, 256, 0, stream>>>(ring, total);
    }

    void* args[] = {
        (void*)&inputs, (void*)&w_in, (void*)&w_out, (void*)&p, (void*)&delays,
        (void*)&W, (void*)&w, (void*)&w_signs, (void*)&dmap,
        (void*)&ring, (void*)&cntp, (void*)&hpart, (void*)&inp_pre, (void*)&outp,
        (void*)&use_pre, (void*)&use_W
    };
    hipLaunchCooperativeKernel((const void*)snn_scan,
                               dim3(256), dim3(256), args, 0, stream);
}

// Round 6
// 12842.345 us; speedup vs baseline: 9.9625x; 1.0443x over previous
//
#include <hip/hip_runtime.h>
#include <cstdint>
#include <cstddef>

// Problem constants
#define BB    64
#define TT    400
#define NN    1024
#define NIN   128
#define NOUT  32
#define DD    3
#define LL6   6        // ring length (delays 1,2,4; skew-1 safe needs > maxdelay+1)
#define GG    16       // batch groups
#define BPG   4        // batches per group
#define NT    32       // column tiles
#define KK    3072     // D*N

#define ALPHA_MEM     0.95f
#define ALPHA_MEM_OUT 0.95f
#define ALPHA_P       0.99f

// ---------------------------------------------------------------------------
__global__ void build_W(const float* __restrict__ w,
                        const float* __restrict__ w_signs,
                        const float* __restrict__ dmap,
                        float* __restrict__ W) {
    int idx = blockIdx.x * blockDim.x + threadIdx.x;
    if (idx >= DD * NN * NN) return;
    int en = idx % (NN * NN);
    int e  = en / NN;
    W[idx] = dmap[idx] * (w_signs[e] * fabsf(w[en]));
}

// inp_pre laid out [t][b][n]
__global__ void gemm_in(const float* __restrict__ inputs,
                        const float* __restrict__ w_in,
                        float* __restrict__ inp) {
    int idx = blockIdx.x * blockDim.x + threadIdx.x;
    if (idx >= TT * BB * NN) return;
    int n  = idx & (NN - 1);
    int tb = idx >> 10;
    int b  = tb & 63;
    int t  = tb >> 6;
    const float* row = inputs + ((size_t)b * TT + t) * NIN;
    float acc = 0.0f;
    #pragma unroll 8
    for (int c = 0; c < NIN; ++c)
        acc = fmaf(row[c], w_in[c * NN + n], acc);
    inp[idx] = acc;
}

// zero through the coherent point so agent-scope readers see it
__global__ void zero_sc1(float* __restrict__ p, int n) {
    int i = blockIdx.x * blockDim.x + threadIdx.x;
    if (i < n)
        __hip_atomic_store(p + i, 0.0f, __ATOMIC_RELAXED, __HIP_MEMORY_SCOPE_AGENT);
}

// ---------------------------------------------------------------------------
// 512 blocks x 256 threads, 2 blocks/CU (2 waves/SIMD). Block (g=bid>>5,
// tile=bid&31) owns states (4 batches x 32 cols) and computes their full-k
// GEMM. Ring exchange via IF-coherent (agent-scope) ops; one 32-block
// group barrier per step (groups fully independent).
// ---------------------------------------------------------------------------
__global__ __launch_bounds__(256, 2) void snn_scan(
    const float* __restrict__ inputs,
    const float* __restrict__ w_in,
    const float* __restrict__ w_out,
    const float* __restrict__ p,
    const int*   __restrict__ delays,
    const float* __restrict__ W,        // (KK,NN) materialized (use_W)
    const float* __restrict__ w_raw,
    const float* __restrict__ w_signs,
    const float* __restrict__ dmap,
    float*       __restrict__ ring,     // (LL6,BB,NN)
    int*         __restrict__ cnt,      // (GG*32) padded barrier counters
    float*       __restrict__ hpart,    // (2,NT,BB,NOUT)
    const float* __restrict__ inp_pre,  // (T,B,N) or null
    float*       __restrict__ out,      // (B,T,NOUT)
    int use_pre, int use_W)
{
    __shared__ __align__(16) float sa[KK * BPG];   // 48 KB; aliased as red[] post-GEMM
    __shared__ float w_out_s[32 * NOUT];           // 4 KB
    __shared__ float spk_s[BPG * 32];              // 512 B
    __shared__ float s_sign[NN];                   // 4 KB (fallback)
    __shared__ float s_in[BPG * NIN];              // 2 KB (fallback)

    const int bid  = blockIdx.x;
    const int g    = bid >> 5;          // 0..15
    const int tile = bid & 31;          // 0..31 (bid%8 = tile%8 -> XCD locality)
    const int tid  = threadIdx.x;
    const int lane = tid & 63;
    const int wv   = tid >> 6;

    const bool st = (tid < BPG * 32);   // 128 state threads
    const int  sb = tid >> 5;           // batch in group (state role)
    const int  nl = tid & 31;           // col in tile   (state role)

    const int gks = tid >> 3;           // k-split 0..31 (GEMM role)
    const int gcg = tid & 7;            // col group 0..7 (4 cols)

    float mem = 0.0f, wp = 0.0f, r = 0.0f;
    float pn = 0.0f, depr = 0.0f;
    if (st) { pn = p[tile * 32 + nl]; depr = (pn < 0.0f) ? 1.0f : 0.0f; }

    const int d0 = delays[0], d1 = delays[1], d2 = delays[2];

    for (int k = tid; k < 32 * NOUT; k += 256)
        w_out_s[k] = w_out[(tile * 32 + (k >> 5)) * NOUT + (k & 31)];
    if (!use_W)
        for (int k = tid; k < NN; k += 256) s_sign[k] = w_signs[k];
    __syncthreads();

    const float* Wt = W     + tile * 32 + gcg * 4;
    const float* Dt = dmap  + tile * 32 + gcg * 4;
    const float* Rt = w_raw + tile * 32 + gcg * 4;

    for (int t = 0; t < TT; ++t) {
        const int slot_w = t % LL6;
        const int s0 = (t - d0 + 2 * LL6) % LL6;
        const int s1 = (t - d1 + 2 * LL6) % LL6;
        const int s2 = (t - d2 + 2 * LL6) % LL6;

        // ---- phase 1: spike, publish ring (IF), wp update, ia prefetch
        bool  spk = false;
        float ia  = 0.0f;
        if (st) {
            spk = (mem - 1.0f) > 0.0f;
            const float a = spk ? (1.0f + wp) : 0.0f;
            __hip_atomic_store(ring + (((size_t)slot_w * BB + g * BPG + sb) << 10)
                                    + tile * 32 + nl,
                               a, __ATOMIC_RELAXED, __HIP_MEMORY_SCOPE_AGENT);
            wp = ALPHA_P * wp + (spk ? pn * (1.0f + depr * wp) : 0.0f);
            spk_s[tid] = spk ? 1.0f : 0.0f;
            if (use_pre)
                ia = inp_pre[((size_t)t * BB + g * BPG + sb) * NN + tile * 32 + nl];
        }
        if (!use_pre) {
            for (int k = tid; k < BPG * NIN; k += 256) {
                int b2 = k >> 7, c = k & 127;
                s_in[k] = inputs[((size_t)(g * BPG + b2) * TT + t) * NIN + c];
            }
        }
        __syncthreads();

        // ---- phase 2: readout partial for this tile
        if (st) {
            float h = 0.0f;
            #pragma unroll
            for (int n2 = 0; n2 < 32; ++n2)
                h = fmaf(spk_s[sb * 32 + n2], w_out_s[n2 * 32 + nl], h);
            __hip_atomic_store(hpart + ((((size_t)(t & 1) * NT + tile) * BB)
                                        + g * BPG + sb) * NOUT + nl,
                               h, __ATOMIC_RELAXED, __HIP_MEMORY_SCOPE_AGENT);
            if (!use_pre) {
                #pragma unroll 8
                for (int c = 0; c < NIN; ++c)
                    ia = fmaf(s_in[sb * NIN + c], w_in[c * NN + tile * 32 + nl], ia);
            }
        }
        __syncthreads();   // all waves' IF stores drained (vmcnt 0) before barrier

        // ---- group barrier: 32 blocks, one RMW each
        if (tid == 0) {
            __hip_atomic_fetch_add(&cnt[g * 32], 1, __ATOMIC_RELEASE,
                                   __HIP_MEMORY_SCOPE_AGENT);
            const int target = 32 * (t + 1);
            while (__hip_atomic_load(&cnt[g * 32], __ATOMIC_RELAXED,
                                     __HIP_MEMORY_SCOPE_AGENT) < target)
                __builtin_amdgcn_s_sleep(2);
        }
        __syncthreads();

        // ---- readout (tile-0 block of each group): integrate step t
        if (tile == 0 && st) {
            float h = 0.0f;
            for (int k3 = 0; k3 < NT; ++k3)
                h += __hip_atomic_load(hpart + ((((size_t)(t & 1) * NT + k3) * BB)
                                                + g * BPG + sb) * NOUT + nl,
                                       __ATOMIC_RELAXED, __HIP_MEMORY_SCOPE_AGENT);
            r = ALPHA_MEM_OUT * r + h;
            out[((size_t)(g * BPG + sb) * TT + t) * NOUT + nl] = r;
        }

        // ---- stage A transposed: sa[k*4 + b], 64B global segments, 2-way LDS
        {
            const int b2 = lane >> 4;       // batch 0..3
            const int eo = lane & 15;       // e offset within 16-chunk
            #pragma unroll 8
            for (int i = 0; i < 48; ++i) {
                const int c  = i * 4 + wv;          // 16-wide k-chunk 0..191
                const int kl = c * 16 + eo;         // k index 0..3071
                const int d  = kl >> 10;
                const int e  = kl & 1023;
                const int sl = (d == 0) ? s0 : ((d == 1) ? s1 : s2);
                const float v = __hip_atomic_load(
                    ring + (((size_t)sl * BB + g * BPG + b2) << 10) + e,
                    __ATOMIC_RELAXED, __HIP_MEMORY_SCOPE_AGENT);
                sa[kl * 4 + b2] = v;
            }
        }
        __syncthreads();

        // ---- GEMM: per thread 4 batches x 4 cols, k interleaved (gks + 32i)
        float4 acc0 = {0,0,0,0}, acc1 = {0,0,0,0}, acc2 = {0,0,0,0}, acc3 = {0,0,0,0};
        if (use_W) {
            #pragma unroll 4
            for (int i = 0; i < 96; ++i) {
                const int kk = gks + (i << 5);
                const float4 av = *(const float4*)&sa[kk << 2];          // 4 batches (broadcast)
                const float4 wv4 = *(const float4*)(Wt + ((size_t)kk << 10)); // 4 cols (L2)
                acc0.x = fmaf(av.x, wv4.x, acc0.x); acc0.y = fmaf(av.x, wv4.y, acc0.y);
                acc0.z = fmaf(av.x, wv4.z, acc0.z); acc0.w = fmaf(av.x, wv4.w, acc0.w);
                acc1.x = fmaf(av.y, wv4.x, acc1.x); acc1.y = fmaf(av.y, wv4.y, acc1.y);
                acc1.z = fmaf(av.y, wv4.z, acc1.z); acc1.w = fmaf(av.y, wv4.w, acc1.w);
                acc2.x = fmaf(av.z, wv4.x, acc2.x); acc2.y = fmaf(av.z, wv4.y, acc2.y);
                acc2.z = fmaf(av.z, wv4.z, acc2.z); acc2.w = fmaf(av.z, wv4.w, acc2.w);
                acc3.x = fmaf(av.w, wv4.x, acc3.x); acc3.y = fmaf(av.w, wv4.y, acc3.y);
                acc3.z = fmaf(av.w, wv4.z, acc3.z); acc3.w = fmaf(av.w, wv4.w, acc3.w);
            }
        } else {
            #pragma unroll 2
            for (int i = 0; i < 96; ++i) {
                const int kk = gks + (i << 5);
                const int e  = kk & 1023;
                const float sg = s_sign[e];
                const float4 dm = *(const float4*)(Dt + ((size_t)kk << 10));
                const float4 wr = *(const float4*)(Rt + ((size_t)e << 10));
                float4 wv4;
                wv4.x = dm.x * (sg * fabsf(wr.x));
                wv4.y = dm.y * (sg * fabsf(wr.y));
                wv4.z = dm.z * (sg * fabsf(wr.z));
                wv4.w = dm.w * (sg * fabsf(wr.w));
                const float4 av = *(const float4*)&sa[kk << 2];
                acc0.x = fmaf(av.x, wv4.x, acc0.x); acc0.y = fmaf(av.x, wv4.y, acc0.y);
                acc0.z = fmaf(av.x, wv4.z, acc0.z); acc0.w = fmaf(av.x, wv4.w, acc0.w);
                acc1.x = fmaf(av.y, wv4.x, acc1.x); acc1.y = fmaf(av.y, wv4.y, acc1.y);
                acc1.z = fmaf(av.y, wv4.z, acc1.z); acc1.w = fmaf(av.y, wv4.w, acc1.w);
                acc2.x = fmaf(av.z, wv4.x, acc2.x); acc2.y = fmaf(av.z, wv4.y, acc2.y);
                acc2.z = fmaf(av.z, wv4.z, acc2.z); acc2.w = fmaf(av.z, wv4.w, acc2.w);
                acc3.x = fmaf(av.w, wv4.x, acc3.x); acc3.y = fmaf(av.w, wv4.y, acc3.y);
                acc3.z = fmaf(av.w, wv4.z, acc3.z); acc3.w = fmaf(av.w, wv4.w, acc3.w);
            }
        }
        __syncthreads();             // sa reads done; alias as red

        float* red = sa;             // red[o][33], o = b2*32 + gcg*4 + j  (o<128)
        {
            const int o0 = gcg * 4;
            red[(0 * 32 + o0 + 0) * 33 + gks] = acc0.x;
            red[(0 * 32 + o0 + 1) * 33 + gks] = acc0.y;
            red[(0 * 32 + o0 + 2) * 33 + gks] = acc0.z;
            red[(0 * 32 + o0 + 3) * 33 + gks] = acc0.w;
            red[(1 * 32 + o0 + 0) * 33 + gks] = acc1.x;
            red[(1 * 32 + o0 + 1) * 33 + gks] = acc1.y;
            red[(1 * 32 + o0 + 2) * 33 + gks] = acc1.z;
            red[(1 * 32 + o0 + 3) * 33 + gks] = acc1.w;
            red[(2 * 32 + o0 + 0) * 33 + gks] = acc2.x;
            red[(2 * 32 + o0 + 1) * 33 + gks] = acc2.y;
            red[(2 * 32 + o0 + 2) * 33 + gks] = acc2.z;
            red[(2 * 32 + o0 + 3) * 33 + gks] = acc2.w;
            red[(3 * 32 + o0 + 0) * 33 + gks] = acc3.x;
            red[(3 * 32 + o0 + 1) * 33 + gks] = acc3.y;
            red[(3 * 32 + o0 + 2) * 33 + gks] = acc3.z;
            red[(3 * 32 + o0 + 3) * 33 + gks] = acc3.w;
        }
        __syncthreads();

        if (st) {
            float syn = 0.0f;
            #pragma unroll
            for (int k2 = 0; k2 < 32; ++k2)
                syn += red[tid * 33 + k2];
            mem = ALPHA_MEM * mem + ia + syn - (spk ? 1.0f : 0.0f);
        }
        __syncthreads();             // red reads done before next staging
    }
}

// ---------------------------------------------------------------------------
extern "C" void kernel_launch(void* const* d_in, const int* in_sizes, int n_in,
                              void* d_out, int out_size, void* d_ws, size_t ws_size,
                              hipStream_t stream) {
    const float* inputs  = (const float*)d_in[0];
    const float* w       = (const float*)d_in[1];
    const float* w_in    = (const float*)d_in[2];
    const float* w_out   = (const float*)d_in[3];
    const float* w_signs = (const float*)d_in[4];
    const float* dmap    = (const float*)d_in[5];
    const float* p       = (const float*)d_in[6];
    const int*   delays  = (const int*)d_in[7];
    float*       outp    = (float*)d_out;

    // ws layout (floats): ring | cnt(padded) | hpart | W | inp_pre
    const size_t ring_f = (size_t)LL6 * BB * NN;          // 393216
    const size_t cnt_f  = GG * 32;                        // 512
    const size_t hp_f   = (size_t)2 * NT * BB * NOUT;     // 131072
    const size_t W_f    = (size_t)DD * NN * NN;           // 3145728
    const size_t pre_f  = (size_t)TT * BB * NN;           // 26214400

    float* ws = (float*)d_ws;
    float* ring  = ws;
    int*   cntp  = (int*)(ws + ring_f);
    float* hpart = ws + ring_f + cnt_f;
    size_t used  = ring_f + cnt_f + hp_f;

    int use_W = 0, use_pre = 0;
    float *W = nullptr, *inp_pre = nullptr;
    if (ws_size >= (used + W_f) * 4)   { use_W = 1;   W = ws + used;       used += W_f; }
    if (ws_size >= (used + pre_f) * 4) { use_pre = 1; inp_pre = ws + used; used += pre_f; }

    if (use_W) {
        const int total = DD * NN * NN;
        build_W<<<(total + 255) / 256, 256, 0, stream>>>(w, w_signs, dmap, W);
    }
    if (use_pre) {
        const int total = TT * BB * NN;
        gemm_in<<<(total + 255) / 256, 256, 0, stream>>>(inputs, w_in, inp_pre);
    }
    {
        const int total = (int)(ring_f + cnt_f);   // ring + counters
        zero_sc1<<<(total + 255) / 256, 256, 0, stream>>>(ring, total);
    }

    void* args[] = {
        (void*)&inputs, (void*)&w_in, (void*)&w_out, (void*)&p, (void*)&delays,
        (void*)&W, (void*)&w, (void*)&w_signs, (void*)&dmap,
        (void*)&ring, (void*)&cntp, (void*)&hpart, (void*)&inp_pre, (void*)&outp,
        (void*)&use_pre, (void*)&use_W
    };
    hipLaunchCooperativeKernel((const void*)snn_scan,
                               dim3(GG * NT), dim3(256), args, 0, stream);
}